// Round 1
// baseline (17507.779 us; speedup 1.0000x reference)
//
#include <hip/hip_runtime.h>
#include <hip/hip_fp16.h>

#define NN 8192
#define DD 32

constexpr float kEps  = 0.1f;
constexpr float kStab = 1e-8f;
constexpr float kMass = 1.0f / 8192.0f;   // mu = nu = 1/n, exact power of 2

// ---------------------------------------------------------------- init u = 1
__global__ void sk_init_u(float* __restrict__ u) {
    u[blockIdx.x * 256 + threadIdx.x] = 1.0f;
}

// ------------------------------------------------- build K = exp(-cost/eps) fp16
// grid (128,128), block 256. Tile: 64 rows (X) x 64 cols (Y).
// LDS layout transposed [d][row] so the micro-GEMM reads are b128, conflict-free.
__global__ __launch_bounds__(256) void sk_build_k(const float* __restrict__ X,
                                                  const float* __restrict__ Y,
                                                  __half* __restrict__ K) {
    __shared__ float xs[DD * 64];
    __shared__ float ys[DD * 64];
    __shared__ float sx[64], sy[64];
    const int t  = threadIdx.x;
    const int r0 = blockIdx.y * 64, c0 = blockIdx.x * 64;

    for (int idx = t; idx < DD * 64; idx += 256) {
        int d = idx >> 6, row = idx & 63;          // xs[d*64+row] == xs[idx]
        xs[idx] = X[(size_t)(r0 + row) * DD + d];
        ys[idx] = Y[(size_t)(c0 + row) * DD + d];
    }
    __syncthreads();
    if (t < 64) {
        float s = 0.f;
        for (int d = 0; d < DD; d++) { float v = xs[d * 64 + t]; s = fmaf(v, v, s); }
        sx[t] = s;
    } else if (t < 128) {
        int q = t - 64; float s = 0.f;
        for (int d = 0; d < DD; d++) { float v = ys[d * 64 + q]; s = fmaf(v, v, s); }
        sy[q] = s;
    }
    __syncthreads();

    const int tr = t >> 4, tc = t & 15;            // 16x16 threads, 4x4 outputs each
    float acc[4][4] = {};
    for (int d = 0; d < DD; d++) {
        const float4 xa = *reinterpret_cast<const float4*>(&xs[d * 64 + 4 * tr]);
        const float4 yb = *reinterpret_cast<const float4*>(&ys[d * 64 + 4 * tc]);
        const float xav[4] = {xa.x, xa.y, xa.z, xa.w};
        const float ybv[4] = {yb.x, yb.y, yb.z, yb.w};
#pragma unroll
        for (int a = 0; a < 4; a++)
#pragma unroll
            for (int b = 0; b < 4; b++) acc[a][b] = fmaf(xav[a], ybv[b], acc[a][b]);
    }
#pragma unroll
    for (int a = 0; a < 4; a++) {
        const int r = r0 + 4 * tr + a;
        const float sxa = sx[4 * tr + a];
        float e[4];
#pragma unroll
        for (int b = 0; b < 4; b++) {
            float cost = sxa + sy[4 * tc + b] - 2.0f * acc[a][b];
            cost = fmaxf(cost, 0.0f);
            e[b] = expf(-cost / kEps);
        }
        __half2 lo, hi;
        lo.x = __float2half_rn(e[0]); lo.y = __float2half_rn(e[1]);
        hi.x = __float2half_rn(e[2]); hi.y = __float2half_rn(e[3]);
        uint2 st;
        st.x = *reinterpret_cast<unsigned int*>(&lo);
        st.y = *reinterpret_cast<unsigned int*>(&hi);
        *reinterpret_cast<uint2*>(&K[(size_t)r * NN + c0 + 4 * tc]) = st;
    }
}

// ------------------------------------------------- column sums: raw_out += K^T u
// grid (32 col-chunks, 32 row-chunks), block 256 (4 waves).
// Wave w covers 64 rows x 256 cols; lane l owns cols c0+4l..+3.
__global__ __launch_bounds__(256) void sk_colsum(const __half* __restrict__ K,
                                                 const float* __restrict__ u,
                                                 float* __restrict__ raw_out) {
    __shared__ float us[256];
    __shared__ float red[4 * 256];
    const int t = threadIdx.x, lane = t & 63, w = t >> 6;
    const int c0 = blockIdx.x * 256, r0 = blockIdx.y * 256;
    us[t] = u[r0 + t];
    __syncthreads();

    float a0 = 0.f, a1 = 0.f, a2 = 0.f, a3 = 0.f;
    const __half* p = K + (size_t)(r0 + 64 * w) * NN + c0 + 4 * lane;
    for (int i = 0; i < 64; i++) {
        const float ui = us[64 * w + i];
        uint2 kk = *reinterpret_cast<const uint2*>(p);
        p += NN;
        float2 f0 = __half22float2(*reinterpret_cast<__half2*>(&kk.x));
        float2 f1 = __half22float2(*reinterpret_cast<__half2*>(&kk.y));
        a0 = fmaf(f0.x, ui, a0); a1 = fmaf(f0.y, ui, a1);
        a2 = fmaf(f1.x, ui, a2); a3 = fmaf(f1.y, ui, a3);
    }
    red[w * 256 + 4 * lane + 0] = a0;
    red[w * 256 + 4 * lane + 1] = a1;
    red[w * 256 + 4 * lane + 2] = a2;
    red[w * 256 + 4 * lane + 3] = a3;
    __syncthreads();
    const float s = red[t] + red[256 + t] + red[512 + t] + red[768 + t];
    atomicAdd(&raw_out[c0 + t], s);
}

// ------------------------------------------------- row sums: u_out = m/(K v + stab)
// v computed on the fly: v_j = m/(raw_in[j]+stab), staged in LDS (fp32, 32 KB).
// grid 512, block 256 (4 waves). Wave w handles 4 rows simultaneously so one
// ds_read_b128 of v feeds 4x8B of K. Also zeroes its slice of the idle raw buffer.
__global__ __launch_bounds__(256) void sk_rowsum(const __half* __restrict__ K,
                                                 const float* __restrict__ raw_in,
                                                 float* __restrict__ u_out,
                                                 float* __restrict__ raw_zero) {
    __shared__ float vs[NN];
    const int t = threadIdx.x;
    for (int j = t; j < NN; j += 256) vs[j] = kMass / (raw_in[j] + kStab);
    if (t < 16) raw_zero[blockIdx.x * 16 + t] = 0.0f;
    __syncthreads();

    const int lane = t & 63, w = t >> 6;
    const int rbase = blockIdx.x * 16 + 4 * w;
    float p0 = 0.f, p1 = 0.f, p2 = 0.f, p3 = 0.f;
    const __half* r0p = K + (size_t)(rbase + 0) * NN + 4 * lane;
    const __half* r1p = r0p + NN;
    const __half* r2p = r1p + NN;
    const __half* r3p = r2p + NN;
    for (int s = 0; s < NN / 256; s++) {
        const float4 v4 = *reinterpret_cast<const float4*>(&vs[4 * lane + 256 * s]);
        uint2 k0 = *reinterpret_cast<const uint2*>(r0p + 256 * s);
        uint2 k1 = *reinterpret_cast<const uint2*>(r1p + 256 * s);
        uint2 k2 = *reinterpret_cast<const uint2*>(r2p + 256 * s);
        uint2 k3 = *reinterpret_cast<const uint2*>(r3p + 256 * s);
        float2 a, b;
        a = __half22float2(*reinterpret_cast<__half2*>(&k0.x));
        b = __half22float2(*reinterpret_cast<__half2*>(&k0.y));
        p0 = fmaf(a.x, v4.x, p0); p0 = fmaf(a.y, v4.y, p0);
        p0 = fmaf(b.x, v4.z, p0); p0 = fmaf(b.y, v4.w, p0);
        a = __half22float2(*reinterpret_cast<__half2*>(&k1.x));
        b = __half22float2(*reinterpret_cast<__half2*>(&k1.y));
        p1 = fmaf(a.x, v4.x, p1); p1 = fmaf(a.y, v4.y, p1);
        p1 = fmaf(b.x, v4.z, p1); p1 = fmaf(b.y, v4.w, p1);
        a = __half22float2(*reinterpret_cast<__half2*>(&k2.x));
        b = __half22float2(*reinterpret_cast<__half2*>(&k2.y));
        p2 = fmaf(a.x, v4.x, p2); p2 = fmaf(a.y, v4.y, p2);
        p2 = fmaf(b.x, v4.z, p2); p2 = fmaf(b.y, v4.w, p2);
        a = __half22float2(*reinterpret_cast<__half2*>(&k3.x));
        b = __half22float2(*reinterpret_cast<__half2*>(&k3.y));
        p3 = fmaf(a.x, v4.x, p3); p3 = fmaf(a.y, v4.y, p3);
        p3 = fmaf(b.x, v4.z, p3); p3 = fmaf(b.y, v4.w, p3);
    }
    float pr[4] = {p0, p1, p2, p3};
#pragma unroll
    for (int k = 0; k < 4; k++) {
        float p = pr[k];
        for (int off = 32; off > 0; off >>= 1) p += __shfl_down(p, off);
        if (lane == 0) u_out[rbase + k] = kMass / (p + kStab);
    }
}

// ------------------------------------------------- w = sum u_i K_ij v_j cost_ij
// cost recovered as -eps*ln(K_fp16). fp32 per-lane partials -> double block sum.
__global__ __launch_bounds__(256) void sk_wsum(const __half* __restrict__ K,
                                               const float* __restrict__ raw_in,
                                               const float* __restrict__ u,
                                               double* __restrict__ acc_out) {
    __shared__ float vs[NN];
    __shared__ double wred[4];
    const int t = threadIdx.x;
    for (int j = t; j < NN; j += 256) vs[j] = kMass / (raw_in[j] + kStab);
    __syncthreads();

    const int lane = t & 63, w = t >> 6;
    const int rbase = blockIdx.x * 16 + 4 * w;
    double lacc = 0.0;
    for (int rr = 0; rr < 4; rr++) {
        const int r = rbase + rr;
        const float ur = u[r];
        const __half* rowp = K + (size_t)r * NN + 4 * lane;
        float p = 0.f;
        for (int s = 0; s < NN / 256; s++) {
            uint2 kk = *reinterpret_cast<const uint2*>(rowp + 256 * s);
            const float4 v4 = *reinterpret_cast<const float4*>(&vs[4 * lane + 256 * s]);
            float2 f0 = __half22float2(*reinterpret_cast<__half2*>(&kk.x));
            float2 f1 = __half22float2(*reinterpret_cast<__half2*>(&kk.y));
            if (f0.x > 0.f) p = fmaf(f0.x * v4.x, logf(f0.x), p);
            if (f0.y > 0.f) p = fmaf(f0.y * v4.y, logf(f0.y), p);
            if (f1.x > 0.f) p = fmaf(f1.x * v4.z, logf(f1.x), p);
            if (f1.y > 0.f) p = fmaf(f1.y * v4.w, logf(f1.y), p);
        }
        lacc += (double)(ur * p);
    }
    for (int off = 32; off > 0; off >>= 1) lacc += __shfl_down(lacc, off);
    if (lane == 0) wred[w] = lacc;
    __syncthreads();
    if (t == 0) {
        // p accumulated k*v*ln(k); cost = -eps*ln(k)
        double total = -(double)kEps * (wred[0] + wred[1] + wred[2] + wred[3]);
        atomicAdd(acc_out, total);
    }
}

// ------------------------------------------------- combine
__global__ void sk_combine(const double* __restrict__ acc, float* __restrict__ out) {
    if (threadIdx.x == 0)
        out[0] = (float)((acc[0] - 0.5 * acc[1] - 0.5 * acc[2]) / 8192.0);
}

extern "C" void kernel_launch(void* const* d_in, const int* in_sizes, int n_in,
                              void* d_out, int out_size, void* d_ws, size_t ws_size,
                              hipStream_t stream) {
    const float* src = (const float*)d_in[0];
    const float* tgt = (const float*)d_in[1];
    float* out = (float*)d_out;

    char* ws = (char*)d_ws;
    const size_t kbytes = (size_t)NN * NN * sizeof(__half);   // 128 MB
    __half* K    = (__half*)ws;
    float*  u    = (float*)(ws + kbytes);
    float*  raw0 = u + NN;
    float*  raw1 = raw0 + NN;
    double* wacc = (double*)(raw1 + NN);

    hipMemsetAsync(wacc, 0, 3 * sizeof(double), stream);

    const float* pts[3][2] = {{src, tgt}, {src, src}, {tgt, tgt}};
    float* raws[2] = {raw0, raw1};

    for (int tf = 0; tf < 3; tf++) {
        hipMemsetAsync(raw0, 0, 2 * NN * sizeof(float), stream);
        sk_init_u<<<NN / 256, 256, 0, stream>>>(u);
        sk_build_k<<<dim3(128, 128), 256, 0, stream>>>(pts[tf][0], pts[tf][1], K);
        for (int it = 0; it < 100; it++) {
            sk_colsum<<<dim3(32, 32), 256, 0, stream>>>(K, u, raws[it & 1]);
            sk_rowsum<<<512, 256, 0, stream>>>(K, raws[it & 1], u, raws[(it + 1) & 1]);
        }
        // after iter 99: u final; raw1 holds last K^T u (defines final v)
        sk_wsum<<<512, 256, 0, stream>>>(K, raw1, u, &wacc[tf]);
    }
    sk_combine<<<1, 64, 0, stream>>>(wacc, out);
}

// Round 2
// 10206.279 us; speedup vs baseline: 1.7154x; 1.7154x over previous
//
#include <hip/hip_runtime.h>
#include <hip/hip_fp16.h>

#define NN 8192
#define DD 32

constexpr float kEps   = 0.1f;
constexpr float kStab  = 1e-8f;
constexpr float kMass  = 1.0f / 8192.0f;   // mu = nu = 1/n, exact power of 2
constexpr float kInvSc = 1.0f / 256.0f;    // K stored as fp8 of 256*K
constexpr float kLnSc  = 5.545177444479562f; // ln(256)

typedef float v2f __attribute__((ext_vector_type(2)));

// decode 4 fp8 (one dword) -> 4 floats (values are 256*K)
__device__ inline void cvt8x4(unsigned int w, float* out) {
    v2f lo = __builtin_amdgcn_cvt_pk_f32_fp8(w, false);
    v2f hi = __builtin_amdgcn_cvt_pk_f32_fp8(w, true);
    out[0] = lo.x; out[1] = lo.y; out[2] = hi.x; out[3] = hi.y;
}

__device__ inline unsigned int pack8x4(float a, float b, float c, float d) {
    int v = 0;
    v = __builtin_amdgcn_cvt_pk_fp8_f32(a, b, v, false);
    v = __builtin_amdgcn_cvt_pk_fp8_f32(c, d, v, true);
    return (unsigned int)v;
}

// ---------------------------------------------------------------- init u = 1
__global__ void sk_init_u(float* __restrict__ u) {
    u[blockIdx.x * 256 + threadIdx.x] = 1.0f;
}

// ------------------------------------------------- build K8 = fp8(256*exp(-cost/eps))
// grid (128,128), block 256. Tile: 64 rows (X) x 64 cols (Y).
__global__ __launch_bounds__(256) void sk_build_k(const float* __restrict__ X,
                                                  const float* __restrict__ Y,
                                                  unsigned char* __restrict__ K8) {
    __shared__ float xs[DD * 64];
    __shared__ float ys[DD * 64];
    __shared__ float sx[64], sy[64];
    const int t  = threadIdx.x;
    const int r0 = blockIdx.y * 64, c0 = blockIdx.x * 64;

    for (int idx = t; idx < DD * 64; idx += 256) {
        int d = idx >> 6, row = idx & 63;
        xs[idx] = X[(size_t)(r0 + row) * DD + d];
        ys[idx] = Y[(size_t)(c0 + row) * DD + d];
    }
    __syncthreads();
    if (t < 64) {
        float s = 0.f;
        for (int d = 0; d < DD; d++) { float v = xs[d * 64 + t]; s = fmaf(v, v, s); }
        sx[t] = s;
    } else if (t < 128) {
        int q = t - 64; float s = 0.f;
        for (int d = 0; d < DD; d++) { float v = ys[d * 64 + q]; s = fmaf(v, v, s); }
        sy[q] = s;
    }
    __syncthreads();

    const int tr = t >> 4, tc = t & 15;            // 16x16 threads, 4x4 outputs each
    float acc[4][4] = {};
    for (int d = 0; d < DD; d++) {
        const float4 xa = *reinterpret_cast<const float4*>(&xs[d * 64 + 4 * tr]);
        const float4 yb = *reinterpret_cast<const float4*>(&ys[d * 64 + 4 * tc]);
        const float xav[4] = {xa.x, xa.y, xa.z, xa.w};
        const float ybv[4] = {yb.x, yb.y, yb.z, yb.w};
#pragma unroll
        for (int a = 0; a < 4; a++)
#pragma unroll
            for (int b = 0; b < 4; b++) acc[a][b] = fmaf(xav[a], ybv[b], acc[a][b]);
    }
#pragma unroll
    for (int a = 0; a < 4; a++) {
        const int r = r0 + 4 * tr + a;
        const float sxa = sx[4 * tr + a];
        float e[4];
#pragma unroll
        for (int b = 0; b < 4; b++) {
            float cost = sxa + sy[4 * tc + b] - 2.0f * acc[a][b];
            cost = fmaxf(cost, 0.0f);
            e[b] = expf(fmaf(-10.0f, cost, kLnSc));   // 256 * exp(-cost/eps)
        }
        *reinterpret_cast<unsigned int*>(&K8[(size_t)r * NN + c0 + 4 * tc]) =
            pack8x4(e[0], e[1], e[2], e[3]);
    }
}

// ------------------------------------------------- column sums: raw_out += K8^T u
// grid (16 col-chunks of 512, 32 row-chunks of 256), block 256 (4 waves).
// Wave w: 64 rows x 512 cols; lane owns 8 cols (one uint2 = 8 fp8 per row).
__global__ __launch_bounds__(256) void sk_colsum(const unsigned char* __restrict__ K8,
                                                 const float* __restrict__ u,
                                                 float* __restrict__ raw_out) {
    __shared__ float us[256];
    __shared__ float red[4 * 512];
    const int t = threadIdx.x, lane = t & 63, w = t >> 6;
    const int c0 = blockIdx.x * 512, r0 = blockIdx.y * 256;
    us[t] = u[r0 + t];
    __syncthreads();

    float acc[8] = {};
    const unsigned char* p = K8 + (size_t)(r0 + 64 * w) * NN + c0 + 8 * lane;
    for (int i = 0; i < 64; i++) {
        const float ui = us[64 * w + i];
        uint2 kk = *reinterpret_cast<const uint2*>(p);
        p += NN;
        float f[8];
        cvt8x4(kk.x, f);
        cvt8x4(kk.y, f + 4);
#pragma unroll
        for (int j = 0; j < 8; j++) acc[j] = fmaf(f[j], ui, acc[j]);
    }
#pragma unroll
    for (int j = 0; j < 8; j++) red[w * 512 + 8 * lane + j] = acc[j];
    __syncthreads();
    for (int c = t; c < 512; c += 256) {
        const float s = red[c] + red[512 + c] + red[1024 + c] + red[1536 + c];
        atomicAdd(&raw_out[c0 + c], s);
    }
}

// ------------------------------------------------- row sums: u_out = m/(K v + stab)
// raw_in holds 256*(K^T u); v staged in LDS with the scale folded out.
// grid 512, block 256 (4 waves), wave w handles 4 rows; lane owns 4 cols/step.
__global__ __launch_bounds__(256) void sk_rowsum(const unsigned char* __restrict__ K8,
                                                 const float* __restrict__ raw_in,
                                                 float* __restrict__ u_out,
                                                 float* __restrict__ raw_zero) {
    __shared__ float vs[NN];
    const int t = threadIdx.x;
    for (int j = t; j < NN; j += 256)
        vs[j] = kMass * __builtin_amdgcn_rcpf(fmaf(raw_in[j], kInvSc, kStab));
    if (t < 16) raw_zero[blockIdx.x * 16 + t] = 0.0f;
    __syncthreads();

    const int lane = t & 63, w = t >> 6;
    const int rbase = blockIdx.x * 16 + 4 * w;
    float p0 = 0.f, p1 = 0.f, p2 = 0.f, p3 = 0.f;
    const unsigned char* r0p = K8 + (size_t)(rbase + 0) * NN + 4 * lane;
    const unsigned char* r1p = r0p + NN;
    const unsigned char* r2p = r1p + NN;
    const unsigned char* r3p = r2p + NN;
    for (int s = 0; s < 32; s++) {
        const float4 v4 = *reinterpret_cast<const float4*>(&vs[4 * lane + 256 * s]);
        unsigned int k0 = *reinterpret_cast<const unsigned int*>(r0p + 256 * s);
        unsigned int k1 = *reinterpret_cast<const unsigned int*>(r1p + 256 * s);
        unsigned int k2 = *reinterpret_cast<const unsigned int*>(r2p + 256 * s);
        unsigned int k3 = *reinterpret_cast<const unsigned int*>(r3p + 256 * s);
        float f[4];
        cvt8x4(k0, f);
        p0 = fmaf(f[0], v4.x, p0); p0 = fmaf(f[1], v4.y, p0);
        p0 = fmaf(f[2], v4.z, p0); p0 = fmaf(f[3], v4.w, p0);
        cvt8x4(k1, f);
        p1 = fmaf(f[0], v4.x, p1); p1 = fmaf(f[1], v4.y, p1);
        p1 = fmaf(f[2], v4.z, p1); p1 = fmaf(f[3], v4.w, p1);
        cvt8x4(k2, f);
        p2 = fmaf(f[0], v4.x, p2); p2 = fmaf(f[1], v4.y, p2);
        p2 = fmaf(f[2], v4.z, p2); p2 = fmaf(f[3], v4.w, p2);
        cvt8x4(k3, f);
        p3 = fmaf(f[0], v4.x, p3); p3 = fmaf(f[1], v4.y, p3);
        p3 = fmaf(f[2], v4.z, p3); p3 = fmaf(f[3], v4.w, p3);
    }
    float pr[4] = {p0, p1, p2, p3};
#pragma unroll
    for (int k = 0; k < 4; k++) {
        float p = pr[k];
        for (int off = 32; off > 0; off >>= 1) p += __shfl_down(p, off);
        if (lane == 0) u_out[rbase + k] = kMass / (p * kInvSc + kStab);
    }
}

// ------------------------------------------------- w = sum u_i K_ij v_j cost_ij
// cost recovered as -eps*ln(K). K stored as f = 256*K.
__global__ __launch_bounds__(256) void sk_wsum(const unsigned char* __restrict__ K8,
                                               const float* __restrict__ raw_in,
                                               const float* __restrict__ u,
                                               double* __restrict__ acc_out) {
    __shared__ float vs[NN];
    __shared__ double wred[4];
    const int t = threadIdx.x;
    for (int j = t; j < NN; j += 256)
        vs[j] = kMass * __builtin_amdgcn_rcpf(fmaf(raw_in[j], kInvSc, kStab));
    __syncthreads();

    const int lane = t & 63, w = t >> 6;
    const int rbase = blockIdx.x * 16 + 4 * w;
    double lacc = 0.0;
    for (int rr = 0; rr < 4; rr++) {
        const int r = rbase + rr;
        const float ur = u[r];
        const unsigned char* rowp = K8 + (size_t)r * NN + 4 * lane;
        float p = 0.f;
        for (int s = 0; s < 32; s++) {
            unsigned int kk = *reinterpret_cast<const unsigned int*>(rowp + 256 * s);
            const float4 v4 = *reinterpret_cast<const float4*>(&vs[4 * lane + 256 * s]);
            float f[4];
            cvt8x4(kk, f);
            // true k = f/256; accumulate f*v*ln(f/256), scale by 1/256 at the end
            if (f[0] > 0.f) p = fmaf(f[0] * v4.x, logf(f[0] * kInvSc), p);
            if (f[1] > 0.f) p = fmaf(f[1] * v4.y, logf(f[1] * kInvSc), p);
            if (f[2] > 0.f) p = fmaf(f[2] * v4.z, logf(f[2] * kInvSc), p);
            if (f[3] > 0.f) p = fmaf(f[3] * v4.w, logf(f[3] * kInvSc), p);
        }
        lacc += (double)(ur * p) * (double)kInvSc;
    }
    for (int off = 32; off > 0; off >>= 1) lacc += __shfl_down(lacc, off);
    if (lane == 0) wred[w] = lacc;
    __syncthreads();
    if (t == 0) {
        // p accumulated k*v*ln(k); cost = -eps*ln(k)
        double total = -(double)kEps * (wred[0] + wred[1] + wred[2] + wred[3]);
        atomicAdd(acc_out, total);
    }
}

// ------------------------------------------------- combine
__global__ void sk_combine(const double* __restrict__ acc, float* __restrict__ out) {
    if (threadIdx.x == 0)
        out[0] = (float)((acc[0] - 0.5 * acc[1] - 0.5 * acc[2]) / 8192.0);
}

extern "C" void kernel_launch(void* const* d_in, const int* in_sizes, int n_in,
                              void* d_out, int out_size, void* d_ws, size_t ws_size,
                              hipStream_t stream) {
    const float* src = (const float*)d_in[0];
    const float* tgt = (const float*)d_in[1];
    float* out = (float*)d_out;

    char* ws = (char*)d_ws;
    const size_t kbytes = (size_t)NN * NN;            // 64 MB fp8
    unsigned char* K8   = (unsigned char*)ws;
    float*  u    = (float*)(ws + kbytes);
    float*  raw0 = u + NN;
    float*  raw1 = raw0 + NN;
    double* wacc = (double*)(raw1 + NN);

    hipMemsetAsync(wacc, 0, 3 * sizeof(double), stream);

    const float* pts[3][2] = {{src, tgt}, {src, src}, {tgt, tgt}};
    float* raws[2] = {raw0, raw1};

    for (int tf = 0; tf < 3; tf++) {
        hipMemsetAsync(raw0, 0, 2 * NN * sizeof(float), stream);
        sk_init_u<<<NN / 256, 256, 0, stream>>>(u);
        sk_build_k<<<dim3(128, 128), 256, 0, stream>>>(pts[tf][0], pts[tf][1], K8);
        for (int it = 0; it < 100; it++) {
            sk_colsum<<<dim3(16, 32), 256, 0, stream>>>(K8, u, raws[it & 1]);
            sk_rowsum<<<512, 256, 0, stream>>>(K8, raws[it & 1], u, raws[(it + 1) & 1]);
        }
        // after iter 99: u final; raw1 holds last K8^T u (defines final v)
        sk_wsum<<<512, 256, 0, stream>>>(K8, raw1, u, &wacc[tf]);
    }
    sk_combine<<<1, 64, 0, stream>>>(wacc, out);
}

// Round 3
// 7776.865 us; speedup vs baseline: 2.2513x; 1.3124x over previous
//
#include <hip/hip_runtime.h>

#define NN 8192
#define DD 32
// stagger-padded LDS index: +4 floats of pad per 16 (keeps 16B alignment,
// turns 64B-strided b128 bank pattern from 8-way conflict into free 2-way)
#define SIDX(c) ((c) + 4 * ((c) >> 4))

constexpr float kEps   = 0.1f;
constexpr float kStab  = 1e-8f;
constexpr float kMass  = 1.0f / 8192.0f;     // mu = nu = 1/n
constexpr float kInvSc = 1.0f / 256.0f;      // K stored as fp8 of 256*K
constexpr float kLnSc  = 5.545177444479562f; // ln(256)

typedef float v2f __attribute__((ext_vector_type(2)));

__device__ inline void cvt8x4(unsigned int w, float* out) {
    v2f lo = __builtin_amdgcn_cvt_pk_f32_fp8(w, false);
    v2f hi = __builtin_amdgcn_cvt_pk_f32_fp8(w, true);
    out[0] = lo.x; out[1] = lo.y; out[2] = hi.x; out[3] = hi.y;
}
__device__ inline void cvt16(uint4 kk, float* f) {
    cvt8x4(kk.x, f); cvt8x4(kk.y, f + 4); cvt8x4(kk.z, f + 8); cvt8x4(kk.w, f + 12);
}
__device__ inline unsigned int pack8x4(float a, float b, float c, float d) {
    int v = 0;
    v = __builtin_amdgcn_cvt_pk_fp8_f32(a, b, v, false);
    v = __builtin_amdgcn_cvt_pk_fp8_f32(c, d, v, true);
    return (unsigned int)v;
}

// ---------------------------------------------------------------- init u = 1
__global__ void sk_init_u(float* __restrict__ u) {
    u[blockIdx.x * 256 + threadIdx.x] = 1.0f;
}

// -------------------------------- build K8 = fp8(256*exp(-cost/eps)), z = transport
__global__ __launch_bounds__(256) void sk_build_k(const float* __restrict__ src,
                                                  const float* __restrict__ tgt,
                                                  unsigned char* __restrict__ K8,
                                                  int nb) {
    const int z = blockIdx.z;
    const float* X = src; const float* Y = tgt;
    if (nb == 3) { if (z == 1) Y = src; else if (z == 2) { X = tgt; } }
    unsigned char* K = K8 + (size_t)z * NN * NN;

    __shared__ float xs[DD * 64];
    __shared__ float ys[DD * 64];
    __shared__ float sx[64], sy[64];
    const int t  = threadIdx.x;
    const int r0 = blockIdx.y * 64, c0 = blockIdx.x * 64;

    for (int idx = t; idx < DD * 64; idx += 256) {
        int d = idx >> 6, row = idx & 63;
        xs[idx] = X[(size_t)(r0 + row) * DD + d];
        ys[idx] = Y[(size_t)(c0 + row) * DD + d];
    }
    __syncthreads();
    if (t < 64) {
        float s = 0.f;
        for (int d = 0; d < DD; d++) { float v = xs[d * 64 + t]; s = fmaf(v, v, s); }
        sx[t] = s;
    } else if (t < 128) {
        int q = t - 64; float s = 0.f;
        for (int d = 0; d < DD; d++) { float v = ys[d * 64 + q]; s = fmaf(v, v, s); }
        sy[q] = s;
    }
    __syncthreads();

    const int tr = t >> 4, tc = t & 15;
    float acc[4][4] = {};
    for (int d = 0; d < DD; d++) {
        const float4 xa = *reinterpret_cast<const float4*>(&xs[d * 64 + 4 * tr]);
        const float4 yb = *reinterpret_cast<const float4*>(&ys[d * 64 + 4 * tc]);
        const float xav[4] = {xa.x, xa.y, xa.z, xa.w};
        const float ybv[4] = {yb.x, yb.y, yb.z, yb.w};
#pragma unroll
        for (int a = 0; a < 4; a++)
#pragma unroll
            for (int b = 0; b < 4; b++) acc[a][b] = fmaf(xav[a], ybv[b], acc[a][b]);
    }
#pragma unroll
    for (int a = 0; a < 4; a++) {
        const int r = r0 + 4 * tr + a;
        const float sxa = sx[4 * tr + a];
        float e[4];
#pragma unroll
        for (int b = 0; b < 4; b++) {
            float cost = sxa + sy[4 * tc + b] - 2.0f * acc[a][b];
            cost = fmaxf(cost, 0.0f);
            e[b] = expf(fmaf(-10.0f, cost, kLnSc));   // 256 * exp(-cost/eps)
        }
        *reinterpret_cast<unsigned int*>(&K[(size_t)r * NN + c0 + 4 * tc]) =
            pack8x4(e[0], e[1], e[2], e[3]);
    }
}

// -------------------------------- column sums: rc[z] += K[z]^T u[z]
// grid (8 colchunks x 64 rowbands x nb), block 256 (4 waves).
// Wave w: 32 rows x 1024 cols; lane owns 16 cols (one dwordx4 per row).
__global__ __launch_bounds__(256) void sk_colsum(const unsigned char* __restrict__ K8,
                                                 const float* __restrict__ u,
                                                 float* __restrict__ rc_out) {
    __shared__ float us[128];
    __shared__ float red[4 * 1280];   // 4 waves x staggered 1024
    const int t = threadIdx.x, lane = t & 63, w = t >> 6;
    const int z = blockIdx.z;
    const int c0 = blockIdx.x * 1024, r0 = blockIdx.y * 128;
    const unsigned char* K = K8 + (size_t)z * NN * NN;
    if (t < 128) us[t] = u[z * NN + r0 + t];
    __syncthreads();

    float acc[16] = {};
    const unsigned char* p = K + (size_t)(r0 + 32 * w) * NN + c0 + 16 * lane;
    for (int i = 0; i < 32; i += 4) {
        uint4 k0 = *reinterpret_cast<const uint4*>(p);
        uint4 k1 = *reinterpret_cast<const uint4*>(p + (size_t)NN);
        uint4 k2 = *reinterpret_cast<const uint4*>(p + (size_t)2 * NN);
        uint4 k3 = *reinterpret_cast<const uint4*>(p + (size_t)3 * NN);
        p += (size_t)4 * NN;
        const float u0 = us[32 * w + i + 0], u1 = us[32 * w + i + 1];
        const float u2 = us[32 * w + i + 2], u3 = us[32 * w + i + 3];
        float f[16];
        cvt16(k0, f);
#pragma unroll
        for (int j = 0; j < 16; j++) acc[j] = fmaf(f[j], u0, acc[j]);
        cvt16(k1, f);
#pragma unroll
        for (int j = 0; j < 16; j++) acc[j] = fmaf(f[j], u1, acc[j]);
        cvt16(k2, f);
#pragma unroll
        for (int j = 0; j < 16; j++) acc[j] = fmaf(f[j], u2, acc[j]);
        cvt16(k3, f);
#pragma unroll
        for (int j = 0; j < 16; j++) acc[j] = fmaf(f[j], u3, acc[j]);
    }
    float* rw = &red[w * 1280 + 20 * lane];   // SIDX(16*lane) = 20*lane
#pragma unroll
    for (int g = 0; g < 4; g++) {
        float4 v = {acc[4 * g + 0], acc[4 * g + 1], acc[4 * g + 2], acc[4 * g + 3]};
        *reinterpret_cast<float4*>(rw + 4 * g) = v;
    }
    __syncthreads();
    for (int c = t; c < 1024; c += 256) {
        const int sc = SIDX(c);
        const float s = red[sc] + red[1280 + sc] + red[2560 + sc] + red[3840 + sc];
        atomicAdd(&rc_out[z * NN + c0 + c], s);
    }
}

// -------------------------------- row sums: u[z] = m/(K[z] v + stab)
// v_j = m/(rc_j/256 + stab) staged in staggered LDS (40 KB).
// grid (256 x nb), block 256 (4 waves); wave handles 8 rows, lane 16 cols/step.
__global__ __launch_bounds__(256) void sk_rowsum(const unsigned char* __restrict__ K8,
                                                 const float* __restrict__ rc_in,
                                                 float* __restrict__ u_out,
                                                 float* __restrict__ rc_zero) {
    __shared__ float vs[10240];   // staggered 8192
    const int t = threadIdx.x;
    const int z = blockIdx.z;
    const unsigned char* K = K8 + (size_t)z * NN * NN;
    const float* rc = rc_in + z * NN;

#pragma unroll
    for (int q = 0; q < 8; q++) {
        const int j = 4 * t + 1024 * q;
        float4 r = *reinterpret_cast<const float4*>(rc + j);
        float4 g;
        g.x = kMass * __builtin_amdgcn_rcpf(fmaf(r.x, kInvSc, kStab));
        g.y = kMass * __builtin_amdgcn_rcpf(fmaf(r.y, kInvSc, kStab));
        g.z = kMass * __builtin_amdgcn_rcpf(fmaf(r.z, kInvSc, kStab));
        g.w = kMass * __builtin_amdgcn_rcpf(fmaf(r.w, kInvSc, kStab));
        *reinterpret_cast<float4*>(&vs[SIDX(j)]) = g;
    }
    // zero the other rc buffer: grid covers nb*NN floats, 32 per block
    {
        const int flat = blockIdx.z * gridDim.x + blockIdx.x;
        if (t < 32) rc_zero[flat * 32 + t] = 0.0f;
    }
    __syncthreads();

    const int lane = t & 63, w = t >> 6;
    const int rbase = blockIdx.x * 32 + 8 * w;
    float acc[8] = {};
    const unsigned char* rp = K + (size_t)rbase * NN + 16 * lane;
    for (int s = 0; s < 8; s++) {
        const float* vp = &vs[20 * lane + 1280 * s];   // SIDX(16*lane + 1024*s)
        const float4 va = *reinterpret_cast<const float4*>(vp);
        const float4 vb = *reinterpret_cast<const float4*>(vp + 4);
        const float4 vc = *reinterpret_cast<const float4*>(vp + 8);
        const float4 vd = *reinterpret_cast<const float4*>(vp + 12);
        const unsigned char* ps = rp + 1024 * s;
#pragma unroll
        for (int r = 0; r < 8; r++) {
            uint4 kk = *reinterpret_cast<const uint4*>(ps + (size_t)r * NN);
            float f[16];
            cvt16(kk, f);
            float a = acc[r];
            a = fmaf(f[0],  va.x, a); a = fmaf(f[1],  va.y, a);
            a = fmaf(f[2],  va.z, a); a = fmaf(f[3],  va.w, a);
            a = fmaf(f[4],  vb.x, a); a = fmaf(f[5],  vb.y, a);
            a = fmaf(f[6],  vb.z, a); a = fmaf(f[7],  vb.w, a);
            a = fmaf(f[8],  vc.x, a); a = fmaf(f[9],  vc.y, a);
            a = fmaf(f[10], vc.z, a); a = fmaf(f[11], vc.w, a);
            a = fmaf(f[12], vd.x, a); a = fmaf(f[13], vd.y, a);
            a = fmaf(f[14], vd.z, a); a = fmaf(f[15], vd.w, a);
            acc[r] = a;
        }
    }
#pragma unroll
    for (int r = 0; r < 8; r++) {
        float p = acc[r];
        for (int off = 32; off > 0; off >>= 1) p += __shfl_down(p, off);
        if (lane == 0) u_out[z * NN + rbase + r] = kMass / (p * kInvSc + kStab);
    }
}

// -------------------------------- w[z] = sum u_i K_ij v_j cost_ij, cost = -eps*ln(K)
__global__ __launch_bounds__(256) void sk_wsum(const unsigned char* __restrict__ K8,
                                               const float* __restrict__ rc_in,
                                               const float* __restrict__ u,
                                               double* __restrict__ acc_out) {
    __shared__ float vs[10240];
    __shared__ double wred[4];
    const int t = threadIdx.x;
    const int z = blockIdx.z;
    const unsigned char* K = K8 + (size_t)z * NN * NN;
    const float* rc = rc_in + z * NN;
#pragma unroll
    for (int q = 0; q < 8; q++) {
        const int j = 4 * t + 1024 * q;
        float4 r = *reinterpret_cast<const float4*>(rc + j);
        float4 g;
        g.x = kMass * __builtin_amdgcn_rcpf(fmaf(r.x, kInvSc, kStab));
        g.y = kMass * __builtin_amdgcn_rcpf(fmaf(r.y, kInvSc, kStab));
        g.z = kMass * __builtin_amdgcn_rcpf(fmaf(r.z, kInvSc, kStab));
        g.w = kMass * __builtin_amdgcn_rcpf(fmaf(r.w, kInvSc, kStab));
        *reinterpret_cast<float4*>(&vs[SIDX(j)]) = g;
    }
    __syncthreads();

    const int lane = t & 63, w = t >> 6;
    const int rbase = blockIdx.x * 32 + 8 * w;
    float pr[8] = {};
    const unsigned char* rp = K + (size_t)rbase * NN + 16 * lane;
    for (int s = 0; s < 8; s++) {
        const float* vp = &vs[20 * lane + 1280 * s];
        float vv[16];
#pragma unroll
        for (int g = 0; g < 4; g++) {
            float4 v4 = *reinterpret_cast<const float4*>(vp + 4 * g);
            vv[4 * g] = v4.x; vv[4 * g + 1] = v4.y; vv[4 * g + 2] = v4.z; vv[4 * g + 3] = v4.w;
        }
        const unsigned char* ps = rp + 1024 * s;
#pragma unroll
        for (int r = 0; r < 8; r++) {
            uint4 kk = *reinterpret_cast<const uint4*>(ps + (size_t)r * NN);
            float f[16];
            cvt16(kk, f);
            float a = pr[r];
#pragma unroll
            for (int j = 0; j < 16; j++) {
                // term k*v*ln(k): zero when f==0 since f*v==0
                a = fmaf(f[j] * vv[j], __logf(fmaxf(f[j], 1e-30f) * kInvSc), a);
            }
            pr[r] = a;
        }
    }
    double lacc = 0.0;
#pragma unroll
    for (int r = 0; r < 8; r++)
        lacc += (double)(u[z * NN + rbase + r] * pr[r]);
    lacc *= (double)kInvSc;
    for (int off = 32; off > 0; off >>= 1) lacc += __shfl_down(lacc, off);
    if (lane == 0) wred[w] = lacc;
    __syncthreads();
    if (t == 0) {
        double total = -(double)kEps * (wred[0] + wred[1] + wred[2] + wred[3]);
        atomicAdd(&acc_out[z], total);
    }
}

// ------------------------------------------------- combine
__global__ void sk_combine(const double* __restrict__ acc, float* __restrict__ out) {
    if (threadIdx.x == 0)
        out[0] = (float)((acc[0] - 0.5 * acc[1] - 0.5 * acc[2]) / 8192.0);
}

extern "C" void kernel_launch(void* const* d_in, const int* in_sizes, int n_in,
                              void* d_out, int out_size, void* d_ws, size_t ws_size,
                              hipStream_t stream) {
    const float* src = (const float*)d_in[0];
    const float* tgt = (const float*)d_in[1];
    float* out = (float*)d_out;
    char* ws = (char*)d_ws;

    const size_t need3 = 3ull * NN * NN + 16ull * NN * sizeof(float) + 1024;
    const bool batched = ws_size >= need3;
    const int B = batched ? 3 : 1;

    const size_t koff = (size_t)B * NN * NN;
    unsigned char* K8 = (unsigned char*)ws;
    float*  u    = (float*)(ws + koff);
    float*  raw0 = u + (size_t)B * NN;
    float*  raw1 = raw0 + (size_t)B * NN;
    double* wacc = (double*)(raw1 + (size_t)B * NN);
    float* raws[2] = {raw0, raw1};

    hipMemsetAsync(wacc, 0, 3 * sizeof(double), stream);

    if (batched) {
        hipMemsetAsync(raw0, 0, 2ull * 3 * NN * sizeof(float), stream);
        sk_init_u<<<3 * NN / 256, 256, 0, stream>>>(u);
        sk_build_k<<<dim3(128, 128, 3), 256, 0, stream>>>(src, tgt, K8, 3);
        for (int it = 0; it < 100; it++) {
            sk_colsum<<<dim3(8, 64, 3), 256, 0, stream>>>(K8, u, raws[it & 1]);
            sk_rowsum<<<dim3(256, 1, 3), 256, 0, stream>>>(K8, raws[it & 1], u,
                                                           raws[(it + 1) & 1]);
        }
        sk_wsum<<<dim3(256, 1, 3), 256, 0, stream>>>(K8, raw1, u, wacc);
    } else {
        const float* pts[3][2] = {{src, tgt}, {src, src}, {tgt, tgt}};
        for (int tf = 0; tf < 3; tf++) {
            hipMemsetAsync(raw0, 0, 2ull * NN * sizeof(float), stream);
            sk_init_u<<<NN / 256, 256, 0, stream>>>(u);
            sk_build_k<<<dim3(128, 128, 1), 256, 0, stream>>>(pts[tf][0], pts[tf][1], K8, 1);
            for (int it = 0; it < 100; it++) {
                sk_colsum<<<dim3(8, 64, 1), 256, 0, stream>>>(K8, u, raws[it & 1]);
                sk_rowsum<<<dim3(256, 1, 1), 256, 0, stream>>>(K8, raws[it & 1], u,
                                                               raws[(it + 1) & 1]);
            }
            sk_wsum<<<dim3(256, 1, 1), 256, 0, stream>>>(K8, raw1, u, &wacc[tf]);
        }
    }
    sk_combine<<<1, 64, 0, stream>>>(wacc, out);
}